// Round 1
// baseline (204.096 us; speedup 1.0000x reference)
//
#include <hip/hip_runtime.h>

#define NB 32
#define NT 512
#define ND 384
#define DUR_MAX 8
#define MAX_OUT (NT * (DUR_MAX - 1))   // 3584
#define NV (ND / 4)                    // 96 float4 per row

// Kernel 1: per-batch inclusive scan of durations + scatter inverse index map.
__global__ __launch_bounds__(NT) void lr_scan_scatter(
    const int* __restrict__ dur, int* __restrict__ totals, int* __restrict__ idxmap)
{
    __shared__ int s[NT];
    const int b = blockIdx.x;
    const int t = threadIdx.x;

    int d = dur[b * NT + t];
    d = d > 0 ? d : 0;            // patched = max(round(1.0*d), 0) == max(d,0)
    s[t] = d;
    __syncthreads();

    // Hillis-Steele inclusive scan over 512 elements
    #pragma unroll
    for (int off = 1; off < NT; off <<= 1) {
        int v = (t >= off) ? s[t - off] : 0;
        __syncthreads();
        s[t] += v;
        __syncthreads();
    }
    const int cum = s[t];
    const int start = cum - d;

    int* base = idxmap + b * MAX_OUT;
    for (int j = 0; j < d; ++j) base[start + j] = t;

    if (t == NT - 1) totals[b] = cum;
}

// Kernel 2: one thread per output float4. Gather or zero-fill.
__global__ __launch_bounds__(256) void lr_gather(
    const float4* __restrict__ in, const int* __restrict__ totals,
    const int* __restrict__ idxmap, float4* __restrict__ out)
{
    const unsigned g = blockIdx.x * 256u + threadIdx.x;
    const unsigned row = g / NV;           // (b, pos) flattened
    const unsigned col = g - row * NV;
    const unsigned b = row / MAX_OUT;
    const unsigned pos = row - b * MAX_OUT;

    float4 r = make_float4(0.f, 0.f, 0.f, 0.f);
    if ((int)pos < totals[b]) {
        const int idx = idxmap[row];
        r = in[(b * NT + idx) * NV + col];
    }
    out[g] = r;
}

extern "C" void kernel_launch(void* const* d_in, const int* in_sizes, int n_in,
                              void* d_out, int out_size, void* d_ws, size_t ws_size,
                              hipStream_t stream)
{
    const float* x   = (const float*)d_in[0];
    const int*   dur = (const int*)d_in[1];
    float* out = (float*)d_out;

    int* totals = (int*)d_ws;                       // NB ints
    int* idxmap = (int*)((char*)d_ws + 128);        // NB*MAX_OUT ints

    lr_scan_scatter<<<NB, NT, 0, stream>>>(dur, totals, idxmap);

    const unsigned n_vec = (unsigned)NB * MAX_OUT * NV;   // 11,010,048
    lr_gather<<<n_vec / 256, 256, 0, stream>>>(
        (const float4*)x, totals, idxmap, (float4*)out);
}